// Round 18
// baseline (127.769 us; speedup 1.0000x reference)
//
#include <hip/hip_runtime.h>
#include <hip/hip_bf16.h>
#include <stdint.h>

// Problem constants: B=4, L=2048, D=1024, vocab<32, N_GRAM=3
#define LSEQ 2048
#define DDIM 1024

typedef __attribute__((ext_vector_type(8))) short bf16x8;
typedef __attribute__((ext_vector_type(16))) float f32x16;

__device__ __forceinline__ ushort f2bf(float x) {
    uint32_t u = __builtin_bit_cast(uint32_t, x);
    u += 0x7fffu + ((u >> 16) & 1u);   // RNE (inputs finite/normal)
    return (ushort)(u >> 16);
}

__device__ __forceinline__ void stage16(const void* g, void* lds) {
    __builtin_amdgcn_global_load_lds((const __attribute__((address_space(1))) void*)g,
                                     (__attribute__((address_space(3))) void*)lds, 16, 0, 0);
}

// R9-proven swizzle for LDS-staged operands (Hb, W1t): row-major bf16, 2048B row
// stride; within each 128B k-block the 16B slot is XORed with (row&7). Baked into
// the global layout by producers (rule 21); LDS readers apply the same XOR.
__device__ __forceinline__ int swz_off(int row, int k) {
    return row * 2048 + ((k >> 6) << 7) + ((((k >> 3) & 7) ^ (row & 7)) << 4) + ((k & 7) << 1);
}

// R7/R15-proven fragment-major layout for register-direct operands (W2F, PactF):
//   F[blk][k16][lane][j] = M[blk*32 + (lane&31)][k16*16 + (lane>>5)*8 + j]
// One 32x16 fragment = 64 lanes x 16B contiguous -> coalesced L2 read, no LDS.
__device__ __forceinline__ size_t frag_off(int blk, int k16, int lane) {
    return ((size_t)(blk * 64 + k16) * 64 + lane) * 16;
}

// ------- Kernel 1 (prep): EXACT R17 (proven) -------------------------------------
// blocks [0,512): 32 groups x 16 REDUNDANT blocks: identical ballot-ranked active
//   list (cap 32/group, R12-proven); block g handles pooled entries e%16==g.
// [512,768): W1 -> W1t swizzled. [768,1024): W2 -> W2F frag-major. rest: H -> Hb.
__global__ __launch_bounds__(256) void prep(const float* __restrict__ H,
                                            const int* __restrict__ ids,
                                            const float* __restrict__ W1,
                                            const float* __restrict__ W2,
                                            char* __restrict__ Hb,
                                            char* __restrict__ W1t,
                                            char* __restrict__ W2F,
                                            char* __restrict__ PactF,
                                            int* __restrict__ lrow,
                                            int* __restrict__ pcnt) {
    const int bid = blockIdx.x;
    const int tid = threadIdx.x;
    if (bid < 512) {
        __shared__ __align__(16) int sk[LSEQ];
        __shared__ __align__(16) int kk[LSEQ];
        __shared__ unsigned long long wmask[4];
        __shared__ int larow[32];
        __shared__ unsigned bm[8];
        const int grp = bid >> 4, g = bid & 15;
        const int b = grp >> 3, chunk = grp & 7;
        const int base = b * LSEQ;
        const int lane = tid & 63, wid = tid >> 6;

        for (int c = tid; c < LSEQ; c += 256) sk[c] = ids[base + c];
        __syncthreads();
        for (int c = tid; c < LSEQ; c += 256)
            kk[c] = c >= 2 ? ((sk[c - 2] << 10) | (sk[c - 1] << 5) | sk[c]) : 0;
        __syncthreads();

        const int i = chunk * 256 + tid;
        const int ki = kk[i];
        int cnt = 0;
        const int4* k4 = (const int4*)kk;
        const int nq = i >> 2;
        for (int q = 0; q < nq; ++q) {
            int4 v = k4[q];
            cnt += (v.x == ki) + (v.y == ki) + (v.z == ki) + (v.w == ki);
        }
        for (int j2 = nq << 2; j2 < i; ++j2) cnt += (kk[j2] == ki);

        unsigned long long m = __ballot(cnt > 0);
        if (lane == 0) wmask[wid] = m;
        __syncthreads();
        int rank = (int)__popcll(m & ((1ull << lane) - 1ull));
        #pragma unroll
        for (int w = 0; w < 4; ++w) if (w < wid) rank += (int)__popcll(wmask[w]);
        const int na0 = (int)(__popcll(wmask[0]) + __popcll(wmask[1]) +
                              __popcll(wmask[2]) + __popcll(wmask[3]));
        const int na = na0 > 32 ? 32 : na0;
        if (cnt > 0 && rank < 32) larow[rank] = tid;
        if (g == 0 && cnt > 0 && rank < 32) lrow[grp * 32 + rank] = tid;
        if (g == 0 && tid == 0) pcnt[grp] = na;
        __syncthreads();

        const float4* H4 = (const float4*)H;
        for (int e = g; e < na; e += 16) {
            const int i2 = chunk * 256 + larow[e];
            const int ki2 = kk[i2];
            float4 acc = make_float4(0.f, 0.f, 0.f, 0.f);
            int count = 0;
            for (int j0 = 0; j0 < i2; j0 += 256) {
                if (tid < 8) bm[tid] = 0u;
                __syncthreads();
                int j = j0 + tid;
                if (j < i2 && kk[j] == ki2)
                    atomicOr(&bm[tid >> 5], 1u << (tid & 31));
                __syncthreads();
                #pragma unroll
                for (int w = 0; w < 8; ++w) {
                    unsigned mm2 = bm[w];
                    while (mm2) {
                        int bit = __ffs(mm2) - 1;
                        mm2 &= mm2 - 1;
                        int j2 = j0 + w * 32 + bit;
                        count++;
                        float4 h = H4[(size_t)(base + j2) * (DDIM / 4) + tid];
                        acc.x += h.x; acc.y += h.y; acc.z += h.z; acc.w += h.w;
                    }
                }
                __syncthreads();
            }
            float s2 = 1.0f / (float)(count > 0 ? count : 1);
            ushort4 o;
            o.x = f2bf(acc.x * s2); o.y = f2bf(acc.y * s2);
            o.z = f2bf(acc.z * s2); o.w = f2bf(acc.w * s2);
            const int c4 = tid * 4;
            const int flane = e + ((c4 >> 3) & 1) * 32;
            *(ushort4*)(PactF + frag_off(grp, c4 >> 4, flane) + (c4 & 7) * 2) = o;
        }
    } else if (bid < 768) {
        int r2 = bid - 512;
        int k0 = (r2 & 15) * 64, n0 = (r2 >> 4) * 64;
        __shared__ ushort t[64][65];
        #pragma unroll
        for (int it = 0; it < 16; ++it) {
            int idx = it * 256 + tid;
            int r = idx >> 6, c = idx & 63;
            t[c][r] = f2bf(W1[(size_t)(k0 + r) * DDIM + n0 + c]);
        }
        __syncthreads();
        #pragma unroll
        for (int it = 0; it < 4; ++it) {
            int idx = it * 256 + tid;
            int r = idx >> 4, gg = idx & 15;
            ushort4 v;
            v.x = t[r][gg * 4]; v.y = t[r][gg * 4 + 1];
            v.z = t[r][gg * 4 + 2]; v.w = t[r][gg * 4 + 3];
            *(ushort4*)(W1t + swz_off(n0 + r, k0 + gg * 4)) = v;
        }
    } else if (bid < 1024) {
        int r2 = bid - 768;
        int k0 = (r2 & 15) * 64, n0 = (r2 >> 4) * 64;
        __shared__ ushort t[64][65];
        #pragma unroll
        for (int it = 0; it < 16; ++it) {
            int idx = it * 256 + tid;
            int r = idx >> 6, c = idx & 63;
            t[c][r] = f2bf(W2[(size_t)(k0 + r) * DDIM + n0 + c]);   // t[n'][k']
        }
        __syncthreads();
        #pragma unroll
        for (int it = 0; it < 4; ++it) {
            int idx = it * 256 + tid;
            int r = idx >> 4, gg = idx & 15;
            int n = n0 + r, k = k0 + gg * 4;
            ushort4 v;
            v.x = t[r][gg * 4]; v.y = t[r][gg * 4 + 1];
            v.z = t[r][gg * 4 + 2]; v.w = t[r][gg * 4 + 3];
            int flane = (n & 31) + ((k >> 3) & 1) * 32;
            *(ushort4*)(W2F + frag_off(n >> 5, k >> 4, flane) + (k & 7) * 2) = v;
        }
    } else {
        int r0 = (bid - 1024) * 8;
        #pragma unroll
        for (int rr = 0; rr < 8; ++rr) {
            int row = r0 + rr;
            float4 h = *(const float4*)(H + (size_t)row * DDIM + tid * 4);
            ushort4 o;
            o.x = f2bf(h.x); o.y = f2bf(h.y); o.z = f2bf(h.z); o.w = f2bf(h.w);
            *(ushort4*)(Hb + swz_off(row, tid * 4)) = o;
        }
    }
}

// ------- Kernel 2 (main): m97-shape port — 128x128 tile, 4 waves, SINGLE buffer --
// Grid 512 (= 2-3 blocks/CU via launch_bounds(256,3)): inter-block TLP hides the
// per-step full drain (m97: 874-912 TF at this structure). Per step: {8 glds +
// thin frag loads -> vmcnt(0) -> barrier -> 16 fat MFMA + 4 thin MFMA -> barrier}.
// Thin sparse P@W2 register-direct (R15-proven); epilogue gathers via half-group
// inverse map. XCD: bid&7 owns a 1024-row slab x all 8 col-tiles.
__global__ __launch_bounds__(256, 3) void gemm_main(
    const char* __restrict__ Hb,
    const char* __restrict__ W1t,
    const char* __restrict__ PactF,
    const char* __restrict__ W2F,
    const float* __restrict__ b1,
    const float* __restrict__ b2,
    const int* __restrict__ lrow,
    const int* __restrict__ pcnt,
    float* __restrict__ out)
{
    __shared__ __align__(128) char smem[32768];   // As 16KB | Bs 16KB (aliased in epi)

    const int tid = threadIdx.x;
    const int lane = tid & 63;
    const int wid = tid >> 6;          // 0..3
    const int wr = wid >> 1, wc = wid & 1;
    const int l31 = lane & 31;
    const int hi2 = lane >> 5;
    const int x7 = l31 & 7;

    const int bid = blockIdx.x;
    const int j = bid >> 3;                               // 0..63
    const int row0 = ((bid & 7) * 8 + (j >> 3)) * 128;    // xcd-contiguous M
    const int col0 = (j & 7) * 128;
    const int grp = row0 >> 8;          // 256-row scan group containing this tile
    const int h0 = row0 & 255;          // 0 or 128: our half within the group
    const int colblk = col0 >> 5;

    f32x16 acc[2][2];
    #pragma unroll
    for (int mm = 0; mm < 2; ++mm)
        #pragma unroll
        for (int nn = 0; nn < 2; ++nn)
            #pragma unroll
            for (int q = 0; q < 16; ++q) acc[mm][nn][q] = 0.f;
    f32x16 mini;
    #pragma unroll
    for (int q = 0; q < 16; ++q) mini[q] = 0.f;

    char* As = smem;
    char* Bs = smem + 16384;
    const int o_lin = wid * 1024 + lane * 16;   // [0,4KB): one issue = 32 rows
    const int srow = o_lin >> 7;
    const int sbyte = o_lin & 127;

    #pragma unroll 1
    for (int t = 0; t < 16; ++t) {
        const int kb = t << 7;
        // stage A (128x64 bf16 = 16KB, 4 issues) + B (16KB, 4 issues)
        #pragma unroll
        for (int c = 0; c < 4; ++c)
            stage16(Hb + (size_t)(row0 + c * 32 + srow) * 2048 + kb + sbyte,
                    As + c * 4096 + wid * 1024);
        #pragma unroll
        for (int c = 0; c < 4; ++c)
            stage16(W1t + (size_t)(col0 + c * 32 + srow) * 2048 + kb + sbyte,
                    Bs + c * 4096 + wid * 1024);
        // thin P-path fragment loads (register-direct; all 4 waves, strip nn=wid)
        bf16x8 pa0, pa1, pa2, pa3, wb0, wb1, wb2, wb3;
        {
            const int k16 = t * 4;
            pa0 = *(const bf16x8*)(PactF + frag_off(grp, k16 + 0, lane));
            pa1 = *(const bf16x8*)(PactF + frag_off(grp, k16 + 1, lane));
            pa2 = *(const bf16x8*)(PactF + frag_off(grp, k16 + 2, lane));
            pa3 = *(const bf16x8*)(PactF + frag_off(grp, k16 + 3, lane));
            wb0 = *(const bf16x8*)(W2F + frag_off(colblk + wid, k16 + 0, lane));
            wb1 = *(const bf16x8*)(W2F + frag_off(colblk + wid, k16 + 1, lane));
            wb2 = *(const bf16x8*)(W2F + frag_off(colblk + wid, k16 + 2, lane));
            wb3 = *(const bf16x8*)(W2F + frag_off(colblk + wid, k16 + 3, lane));
        }
        asm volatile("s_waitcnt vmcnt(0)" ::: "memory");   // drain hidden by co-resident blocks
        __builtin_amdgcn_s_barrier();

        // fat 16 MFMA
        bf16x8 af[2][4], bf[2][4];
        #pragma unroll
        for (int ks = 0; ks < 4; ++ks) {
            const int so = ((ks * 2 + hi2) ^ x7) << 4;
            #pragma unroll
            for (int mm = 0; mm < 2; ++mm)
                af[mm][ks] = *(const bf16x8*)(As + (wr * 64 + mm * 32 + l31) * 128 + so);
            #pragma unroll
            for (int nn = 0; nn < 2; ++nn)
                bf[nn][ks] = *(const bf16x8*)(Bs + (wc * 64 + nn * 32 + l31) * 128 + so);
        }
        __builtin_amdgcn_s_setprio(1);
        #pragma unroll
        for (int ks = 0; ks < 4; ++ks)
            #pragma unroll
            for (int mm = 0; mm < 2; ++mm)
                #pragma unroll
                for (int nn = 0; nn < 2; ++nn)
                    acc[mm][nn] = __builtin_amdgcn_mfma_f32_32x32x16_bf16(
                        af[mm][ks], bf[nn][ks], acc[mm][nn], 0, 0, 0);
        __builtin_amdgcn_s_setprio(0);
        // thin 4 MFMA
        mini = __builtin_amdgcn_mfma_f32_32x32x16_bf16(pa0, wb0, mini, 0, 0, 0);
        mini = __builtin_amdgcn_mfma_f32_32x32x16_bf16(pa1, wb1, mini, 0, 0, 0);
        mini = __builtin_amdgcn_mfma_f32_32x32x16_bf16(pa2, wb2, mini, 0, 0, 0);
        mini = __builtin_amdgcn_mfma_f32_32x32x16_bf16(pa3, wb3, mini, 0, 0, 0);
        __builtin_amdgcn_s_barrier();     // all waves done reading; safe to restage
    }

    // ---- epilogue: mini -> LDS (aliased), half-group inverse map, gathered write
    __syncthreads();
    float* miniLDS = (float*)smem;          // [32][128] = 16KB
    int* inv = (int*)(smem + 16384);        // [128]
    if (tid < 128) inv[tid] = -1;
    #pragma unroll
    for (int reg = 0; reg < 16; ++reg) {
        int s = (reg & 3) + 8 * (reg >> 2) + 4 * hi2;   // slot row 0..31
        miniLDS[s * 128 + wid * 32 + l31] = mini[reg];
    }
    __syncthreads();
    {
        const int na = pcnt[grp];
        if (tid < na) {
            int rel = lrow[grp * 32 + tid] - h0;
            if (rel >= 0 && rel < 128) inv[rel] = tid;
        }
    }
    __syncthreads();

    #pragma unroll
    for (int mm = 0; mm < 2; ++mm) {
        #pragma unroll
        for (int nn = 0; nn < 2; ++nn) {
            const int cl = wc * 64 + nn * 32 + l31;         // col - col0 (0..127)
            const int c = col0 + cl;
            const float bias = b1[c] + b2[c];
            const int rbase = wr * 64 + mm * 32 + hi2 * 4;  // row - row0 (0..127)
            #pragma unroll
            for (int reg = 0; reg < 16; ++reg) {
                int rl = rbase + (reg & 3) + 8 * (reg >> 2);
                int s = inv[rl];
                float v = acc[mm][nn][reg] + bias;
                if (s >= 0) v += miniLDS[s * 128 + cl];
                out[(size_t)(row0 + rl) * DDIM + c] = v;
            }
        }
    }
}

extern "C" void kernel_launch(void* const* d_in, const int* in_sizes, int n_in,
                              void* d_out, int out_size, void* d_ws, size_t ws_size,
                              hipStream_t stream) {
    const float* H  = (const float*)d_in[0];
    const int*   ids = (const int*)d_in[1];
    const float* W1 = (const float*)d_in[2];
    const float* b1 = (const float*)d_in[3];
    const float* W2 = (const float*)d_in[4];
    const float* b2 = (const float*)d_in[5];
    float* out = (float*)d_out;

    char* ws = (char*)d_ws;
    char* Hb     = ws;                         // 16MB bf16 swizzled
    char* W1t    = ws + (16 << 20);            // 2MB swizzled
    char* W2F    = ws + (18 << 20);            // 2MB fragment-major
    char* PactF  = ws + (20 << 20);            // 2MB fragment-major
    int* lrow    = (int*)(ws + (22 << 20));    // 4KB
    int* pcnt    = (int*)(ws + (22 << 20) + (8 << 10));
    // total ~22MB < proven 36MB; 2 nodes, no memsets

    prep<<<2048, 256, 0, stream>>>(H, ids, W1, W2, Hb, W1t, W2F, PactF, lrow, pcnt);
    gemm_main<<<512, 256, 0, stream>>>(Hb, W1t, PactF, W2F, b1, b2, lrow, pcnt, out);
}

// Round 19
// 54.541 us; speedup vs baseline: 2.3426x; 2.3426x over previous
//
#include <hip/hip_runtime.h>
#include <hip/hip_bf16.h>
#include <stdint.h>

// Problem constants: B=4, L=2048, D=1024, vocab<32, N_GRAM=3
#define LSEQ 2048
#define DDIM 1024

typedef __attribute__((ext_vector_type(8))) short bf16x8;
typedef __attribute__((ext_vector_type(16))) float f32x16;

__device__ __forceinline__ ushort f2bf(float x) {
    uint32_t u = __builtin_bit_cast(uint32_t, x);
    u += 0x7fffu + ((u >> 16) & 1u);   // RNE (inputs finite/normal)
    return (ushort)(u >> 16);
}

__device__ __forceinline__ void stage16(const void* g, void* lds) {
    __builtin_amdgcn_global_load_lds((const __attribute__((address_space(1))) void*)g,
                                     (__attribute__((address_space(3))) void*)lds, 16, 0, 0);
}

// R9-proven swizzle for LDS-staged operands (Hb, W1t): row-major bf16, 2048B row
// stride; within each 128B k-block the 16B slot is XORed with (row&7). Baked into
// the global layout by producers (rule 21); LDS readers apply the same XOR.
__device__ __forceinline__ int swz_off(int row, int k) {
    return row * 2048 + ((k >> 6) << 7) + ((((k >> 3) & 7) ^ (row & 7)) << 4) + ((k & 7) << 1);
}

// R7/R15-proven fragment-major layout for register-direct operands (W2F, PactF):
//   F[blk][k16][lane][j] = M[blk*32 + (lane&31)][k16*16 + (lane>>5)*8 + j]
// One 32x16 fragment = 64 lanes x 16B contiguous -> coalesced L2 read, no LDS.
__device__ __forceinline__ size_t frag_off(int blk, int k16, int lane) {
    return ((size_t)(blk * 64 + k16) * 64 + lane) * 16;
}

// ------- Kernel 1 (prep): 16-redundant scan+pool | W1 swz | W2 frag | H->bf16 ----
// blocks [0,512): 32 groups x 16 REDUNDANT blocks. NEW scan: active(i) =
//   key-in-prior-chunks (4KB LDS bitmap, one atomicOr pass — order-independent,
//   deterministic) OR match within own chunk before i (fixed 64 int4 iters).
//   Replaces the O(i) per-thread backward scan (~8x less serial work).
//   Ballot-ranked active list (cap 32/group, R12-proven); block g handles pooled
//   entries e%16==g; g==0 writes lrow+pcnt.
// [512,768): W1 -> W1t swizzled. [768,1024): W2 -> W2F frag-major. rest: H -> Hb.
__global__ __launch_bounds__(256) void prep(const float* __restrict__ H,
                                            const int* __restrict__ ids,
                                            const float* __restrict__ W1,
                                            const float* __restrict__ W2,
                                            char* __restrict__ Hb,
                                            char* __restrict__ W1t,
                                            char* __restrict__ W2F,
                                            char* __restrict__ PactF,
                                            int* __restrict__ lrow,
                                            int* __restrict__ pcnt) {
    const int bid = blockIdx.x;
    const int tid = threadIdx.x;
    if (bid < 512) {
        __shared__ __align__(16) int sk[LSEQ];
        __shared__ __align__(16) int kk[LSEQ];
        __shared__ unsigned seen[1024];          // 32768-key bitmap (4KB)
        __shared__ unsigned long long wmask[4];
        __shared__ int larow[32];
        __shared__ unsigned bm[8];
        const int grp = bid >> 4, g = bid & 15;
        const int b = grp >> 3, chunk = grp & 7;
        const int base = b * LSEQ;
        const int lane = tid & 63, wid = tid >> 6;

        for (int c = tid; c < LSEQ; c += 256) sk[c] = ids[base + c];
        for (int w = tid; w < 1024; w += 256) seen[w] = 0u;
        __syncthreads();
        for (int c = tid; c < LSEQ; c += 256)
            kk[c] = c >= 2 ? ((sk[c - 2] << 10) | (sk[c - 1] << 5) | sk[c]) : 0;
        __syncthreads();

        // bitmap of keys in prior chunks [0, chunk*256)
        for (int q = tid; q < chunk * 256; q += 256)
            atomicOr(&seen[kk[q] >> 5], 1u << (kk[q] & 31));
        __syncthreads();

        // within-chunk: fixed 64 int4 iterations, predicate (j < i) folded in
        const int i = chunk * 256 + tid;
        const int ki = kk[i];
        int cnt = (seen[ki >> 5] >> (ki & 31)) & 1;
        {
            const int4* k4 = (const int4*)(kk + chunk * 256);
            #pragma unroll 4
            for (int q = 0; q < 64; ++q) {
                int4 v = k4[q];
                int jb = q * 4;
                cnt += (v.x == ki && jb < tid);
                cnt += (v.y == ki && jb + 1 < tid);
                cnt += (v.z == ki && jb + 2 < tid);
                cnt += (v.w == ki && jb + 3 < tid);
            }
        }

        unsigned long long m = __ballot(cnt > 0);
        if (lane == 0) wmask[wid] = m;
        __syncthreads();
        int rank = (int)__popcll(m & ((1ull << lane) - 1ull));
        #pragma unroll
        for (int w = 0; w < 4; ++w) if (w < wid) rank += (int)__popcll(wmask[w]);
        const int na0 = (int)(__popcll(wmask[0]) + __popcll(wmask[1]) +
                              __popcll(wmask[2]) + __popcll(wmask[3]));
        const int na = na0 > 32 ? 32 : na0;   // R12-proven sufficient for this input
        if (cnt > 0 && rank < 32) larow[rank] = tid;
        if (g == 0 && cnt > 0 && rank < 32) lrow[grp * 32 + rank] = tid;
        if (g == 0 && tid == 0) pcnt[grp] = na;
        __syncthreads();

        const float4* H4 = (const float4*)H;
        for (int e = g; e < na; e += 16) {
            const int i2 = chunk * 256 + larow[e];
            const int ki2 = kk[i2];
            float4 acc = make_float4(0.f, 0.f, 0.f, 0.f);
            int count = 0;
            for (int j0 = 0; j0 < i2; j0 += 256) {
                if (tid < 8) bm[tid] = 0u;
                __syncthreads();
                int j = j0 + tid;
                if (j < i2 && kk[j] == ki2)
                    atomicOr(&bm[tid >> 5], 1u << (tid & 31));
                __syncthreads();
                #pragma unroll
                for (int w = 0; w < 8; ++w) {
                    unsigned mm2 = bm[w];
                    while (mm2) {
                        int bit = __ffs(mm2) - 1;
                        mm2 &= mm2 - 1;
                        int j2 = j0 + w * 32 + bit;
                        count++;
                        float4 h = H4[(size_t)(base + j2) * (DDIM / 4) + tid];
                        acc.x += h.x; acc.y += h.y; acc.z += h.z; acc.w += h.w;
                    }
                }
                __syncthreads();
            }
            float s2 = 1.0f / (float)(count > 0 ? count : 1);
            ushort4 o;
            o.x = f2bf(acc.x * s2); o.y = f2bf(acc.y * s2);
            o.z = f2bf(acc.z * s2); o.w = f2bf(acc.w * s2);
            const int c4 = tid * 4;
            const int flane = e + ((c4 >> 3) & 1) * 32;
            *(ushort4*)(PactF + frag_off(grp, c4 >> 4, flane) + (c4 & 7) * 2) = o;
        }
    } else if (bid < 768) {
        int r2 = bid - 512;
        int k0 = (r2 & 15) * 64, n0 = (r2 >> 4) * 64;
        __shared__ ushort t[64][65];
        #pragma unroll
        for (int it = 0; it < 16; ++it) {
            int idx = it * 256 + tid;
            int r = idx >> 6, c = idx & 63;
            t[c][r] = f2bf(W1[(size_t)(k0 + r) * DDIM + n0 + c]);
        }
        __syncthreads();
        #pragma unroll
        for (int it = 0; it < 4; ++it) {
            int idx = it * 256 + tid;
            int r = idx >> 4, gg = idx & 15;
            ushort4 v;
            v.x = t[r][gg * 4]; v.y = t[r][gg * 4 + 1];
            v.z = t[r][gg * 4 + 2]; v.w = t[r][gg * 4 + 3];
            *(ushort4*)(W1t + swz_off(n0 + r, k0 + gg * 4)) = v;
        }
    } else if (bid < 1024) {
        int r2 = bid - 768;
        int k0 = (r2 & 15) * 64, n0 = (r2 >> 4) * 64;
        __shared__ ushort t[64][65];
        #pragma unroll
        for (int it = 0; it < 16; ++it) {
            int idx = it * 256 + tid;
            int r = idx >> 6, c = idx & 63;
            t[c][r] = f2bf(W2[(size_t)(k0 + r) * DDIM + n0 + c]);   // t[n'][k']
        }
        __syncthreads();
        #pragma unroll
        for (int it = 0; it < 4; ++it) {
            int idx = it * 256 + tid;
            int r = idx >> 4, gg = idx & 15;
            int n = n0 + r, k = k0 + gg * 4;
            ushort4 v;
            v.x = t[r][gg * 4]; v.y = t[r][gg * 4 + 1];
            v.z = t[r][gg * 4 + 2]; v.w = t[r][gg * 4 + 3];
            int flane = (n & 31) + ((k >> 3) & 1) * 32;
            *(ushort4*)(W2F + frag_off(n >> 5, k >> 4, flane) + (k & 7) * 2) = v;
        }
    } else {
        int r0 = (bid - 1024) * 8;
        #pragma unroll
        for (int rr = 0; rr < 8; ++rr) {
            int row = r0 + rr;
            float4 h = *(const float4*)(H + (size_t)row * DDIM + tid * 4);
            ushort4 o;
            o.x = f2bf(h.x); o.y = f2bf(h.y); o.z = f2bf(h.z); o.w = f2bf(h.w);
            *(ushort4*)(Hb + swz_off(row, tid * 4)) = o;
        }
    }
}

// ------- Kernel 2 (main): out = H@W1 + (b1+b2) + [sparse P@W2 folded in] ---------
// EXACT R15/R17 kernel (proven): 256x128 tile, 16 K-steps, triple-buffer LDS,
// depth-2 prefetch, counted vmcnt(6); thin P-GEMM register-direct under the fat
// MFMA cluster; epilogue gathers mini via lrow inverse map.
__global__ __launch_bounds__(512, 2) void gemm_main(
    const char* __restrict__ Hb,
    const char* __restrict__ W1t,
    const char* __restrict__ PactF,
    const char* __restrict__ W2F,
    const float* __restrict__ b1,
    const float* __restrict__ b2,
    const int* __restrict__ lrow,
    const int* __restrict__ pcnt,
    float* __restrict__ out)
{
    __shared__ __align__(128) char smem[147456];   // 3x32KB A | 3x16KB B (aliased later)

    const int tid = threadIdx.x;
    const int lane = tid & 63;
    const int wid = tid >> 6;
    const int wr = wid >> 1, wc = wid & 1;
    const int l31 = lane & 31;
    const int hi2 = lane >> 5;
    const int x7 = l31 & 7;

    const int bid = blockIdx.x;
    const int j = bid >> 3;
    const int row0 = ((bid & 7) * 4 + (j >> 3)) * 256;
    const int col0 = (j & 7) * 128;
    const int grp = row0 >> 8;          // M-slab == one scan group
    const int colblk = col0 >> 5;

    f32x16 acc[2][2];
    #pragma unroll
    for (int mm = 0; mm < 2; ++mm)
        #pragma unroll
        for (int nn = 0; nn < 2; ++nn)
            #pragma unroll
            for (int q = 0; q < 16; ++q) acc[mm][nn][q] = 0.f;
    f32x16 mini;
    #pragma unroll
    for (int q = 0; q < 16; ++q) mini[q] = 0.f;

    const int o_lin = wid * 1024 + lane * 16;
    const int srow = o_lin >> 7;
    const int sbyte = o_lin & 127;

    char* Acur = smem;           char* Anx1 = smem + 32768;  char* Anx2 = smem + 65536;
    char* Bcur = smem + 98304;   char* Bnx1 = smem + 114688; char* Bnx2 = smem + 131072;

    auto stageB = [&](char* dstB, int kb) {
        #pragma unroll
        for (int c = 0; c < 2; ++c)
            stage16(W1t + (size_t)(col0 + c * 64 + srow) * 2048 + kb + sbyte,
                    dstB + c * 8192 + wid * 1024);
    };
    auto stageA = [&](char* dstA, int kb) {
        #pragma unroll
        for (int c = 0; c < 4; ++c)
            stage16(Hb + (size_t)(row0 + c * 64 + srow) * 2048 + kb + sbyte,
                    dstA + c * 8192 + wid * 1024);
    };
    auto computeFat = [&]() {
        bf16x8 af[2][4], bf[2][4];
        #pragma unroll
        for (int ks = 0; ks < 4; ++ks) {
            const int so = ((ks * 2 + hi2) ^ x7) << 4;
            #pragma unroll
            for (int mm = 0; mm < 2; ++mm)
                af[mm][ks] = *(const bf16x8*)(Acur + (wr * 64 + mm * 32 + l31) * 128 + so);
            #pragma unroll
            for (int nn = 0; nn < 2; ++nn)
                bf[nn][ks] = *(const bf16x8*)(Bcur + (wc * 64 + nn * 32 + l31) * 128 + so);
        }
        __builtin_amdgcn_s_setprio(1);
        #pragma unroll
        for (int ks = 0; ks < 4; ++ks)
            #pragma unroll
            for (int mm = 0; mm < 2; ++mm)
                #pragma unroll
                for (int nn = 0; nn < 2; ++nn)
                    acc[mm][nn] = __builtin_amdgcn_mfma_f32_32x32x16_bf16(
                        af[mm][ks], bf[nn][ks], acc[mm][nn], 0, 0, 0);
        __builtin_amdgcn_s_setprio(0);
    };
    auto rotate = [&]() {
        char* tp;
        tp = Acur; Acur = Anx1; Anx1 = Anx2; Anx2 = tp;
        tp = Bcur; Bcur = Bnx1; Bnx1 = Bnx2; Bnx2 = tp;
    };

    // prologue: stage K-tiles 0,1
    stageA(Acur, 0);        stageB(Bcur, 0);
    stageA(Anx1, 1 << 7);   stageB(Bnx1, 1 << 7);
    asm volatile("s_waitcnt vmcnt(6)" ::: "memory");
    __builtin_amdgcn_s_barrier();

    #pragma unroll 1
    for (int t = 0; t < 16; ++t) {
        // thin P-path loads (waves 0-3 only; nn strip = wid), register-direct
        bf16x8 pa0, pa1, pa2, pa3, wb0, wb1, wb2, wb3;
        if (wid < 4) {
            const int k16 = t * 4;
            pa0 = *(const bf16x8*)(PactF + frag_off(grp, k16 + 0, lane));
            pa1 = *(const bf16x8*)(PactF + frag_off(grp, k16 + 1, lane));
            pa2 = *(const bf16x8*)(PactF + frag_off(grp, k16 + 2, lane));
            pa3 = *(const bf16x8*)(PactF + frag_off(grp, k16 + 3, lane));
            wb0 = *(const bf16x8*)(W2F + frag_off(colblk + wid, k16 + 0, lane));
            wb1 = *(const bf16x8*)(W2F + frag_off(colblk + wid, k16 + 1, lane));
            wb2 = *(const bf16x8*)(W2F + frag_off(colblk + wid, k16 + 2, lane));
            wb3 = *(const bf16x8*)(W2F + frag_off(colblk + wid, k16 + 3, lane));
        }
        if (t < 14) {
            stageA(Anx2, (t + 2) << 7);
            stageB(Bnx2, (t + 2) << 7);
        }
        computeFat();
        if (wid < 4) {   // latency hidden under the fat MFMA cluster
            mini = __builtin_amdgcn_mfma_f32_32x32x16_bf16(pa0, wb0, mini, 0, 0, 0);
            mini = __builtin_amdgcn_mfma_f32_32x32x16_bf16(pa1, wb1, mini, 0, 0, 0);
            mini = __builtin_amdgcn_mfma_f32_32x32x16_bf16(pa2, wb2, mini, 0, 0, 0);
            mini = __builtin_amdgcn_mfma_f32_32x32x16_bf16(pa3, wb3, mini, 0, 0, 0);
        }
        // >=6 VMEM ops issued this iter in every wave -> stage(t+1) provably drained
        asm volatile("s_waitcnt vmcnt(6)" ::: "memory");
        __builtin_amdgcn_s_barrier();
        rotate();
    }

    // ---- epilogue: mini -> LDS, inv map, gathered write ----
    asm volatile("s_waitcnt vmcnt(0)" ::: "memory");
    __syncthreads();                        // safe to alias smem now
    float* miniLDS = (float*)smem;          // [32][128] = 16KB
    int* inv = (int*)(smem + 16384);        // [256]
    const int na = pcnt[grp];
    if (tid < 256) inv[tid] = -1;
    __syncthreads();
    if (tid < na) inv[lrow[grp * 32 + tid]] = tid;
    if (wid < 4) {
        #pragma unroll
        for (int reg = 0; reg < 16; ++reg) {
            int s = (reg & 3) + 8 * (reg >> 2) + 4 * hi2;   // slot row
            miniLDS[s * 128 + wid * 32 + l31] = mini[reg];
        }
    }
    __syncthreads();

    #pragma unroll
    for (int mm = 0; mm < 2; ++mm) {
        #pragma unroll
        for (int nn = 0; nn < 2; ++nn) {
            const int cl = wc * 64 + nn * 32 + l31;         // col - col0
            const int c = col0 + cl;
            const float bias = b1[c] + b2[c];
            const int rbase = wr * 64 + mm * 32 + hi2 * 4;  // row - row0
            #pragma unroll
            for (int reg = 0; reg < 16; ++reg) {
                int rl = rbase + (reg & 3) + 8 * (reg >> 2);
                int s = inv[rl];
                float v = acc[mm][nn][reg] + bias;
                if (s >= 0) v += miniLDS[s * 128 + cl];
                out[(size_t)(row0 + rl) * DDIM + c] = v;
            }
        }
    }
}

extern "C" void kernel_launch(void* const* d_in, const int* in_sizes, int n_in,
                              void* d_out, int out_size, void* d_ws, size_t ws_size,
                              hipStream_t stream) {
    const float* H  = (const float*)d_in[0];
    const int*   ids = (const int*)d_in[1];
    const float* W1 = (const float*)d_in[2];
    const float* b1 = (const float*)d_in[3];
    const float* W2 = (const float*)d_in[4];
    const float* b2 = (const float*)d_in[5];
    float* out = (float*)d_out;

    char* ws = (char*)d_ws;
    char* Hb     = ws;                         // 16MB bf16 swizzled
    char* W1t    = ws + (16 << 20);            // 2MB swizzled
    char* W2F    = ws + (18 << 20);            // 2MB fragment-major
    char* PactF  = ws + (20 << 20);            // 2MB fragment-major
    int* lrow    = (int*)(ws + (22 << 20));    // 4KB
    int* pcnt    = (int*)(ws + (22 << 20) + (8 << 10));
    // total ~22MB < proven 36MB; 2 nodes, no memsets

    prep<<<2048, 256, 0, stream>>>(H, ids, W1, W2, Hb, W1t, W2F, PactF, lrow, pcnt);
    gemm_main<<<256, 512, 0, stream>>>(Hb, W1t, PactF, W2F, b1, b2, lrow, pcnt, out);
}